// Round 8
// baseline (248.896 us; speedup 1.0000x reference)
//
#include <hip/hip_runtime.h>
#include <math.h>

#define IN_DIM 128
#define OUT_DIM 128
#define SIZE_ (IN_DIM*OUT_DIM)
#define BATCH 1024
#define NG 6        // grid points per row
#define NC 8        // coefs per row (NUM+K)
#define JCH 16      // j rows per block (j-loop)
#define BB 8        // b rows per block (4 waves x 2)

typedef float f4 __attribute__((ext_vector_type(4)));

// Uniform-knot KAN forward, j-loop structure — STRICT MINIMAL DIFF on the
// 226.7us session-best baseline. The ONLY change vs baseline: lane->i mapping
// i = q+32c  ->  i = 4q+c (contiguous), so per j: 12 scalar stores -> 3
// dwordx4, 12 scalar scale loads -> 3 dwordx4, coef loads stay 8 (now
// thread-contiguous 128B). Everything else identical: same grid (8 jc x 128
// bc = 1024 blocks), same launch_bounds(256,4), same per-j in-lane add +
// 5-level butterfly + q==0 scalar y_out store, plain stores, simple indexed
// addressing, unroll 1 (R2 showed unroll>=2 clusters ~88 VGPR of f4 loads and
// spills under the 128 cap; R3 showed sched_barrier costs ~20%).
// Rationale: R0/R2/R3/R4/R6/R7 each bundled this remap with another change
// that regressed (scratch, spill, order-pinning, occupancy, blocking); the
// remap itself was never isolated on the proven-best base.
// Numerics bitwise-identical: same 8-FMA dot order, same sequential
// y-accumulation, same butterfly order.
__global__ __launch_bounds__(256, 4) void kan_fused(
    const float* __restrict__ x,          // (BATCH, IN_DIM)
    const float* __restrict__ grid,       // (SIZE, NG)
    const float* __restrict__ coef,       // (SIZE, NC)
    const float* __restrict__ scale_base, // (SIZE,)
    const float* __restrict__ scale_sp,   // (SIZE,)
    const float* __restrict__ mask,       // (SIZE,)
    float* __restrict__ y_out,            // (BATCH, OUT_DIM)
    float* __restrict__ preacts,          // (BATCH, SIZE)
    float* __restrict__ postacts,         // (BATCH, SIZE)
    float* __restrict__ postspline)       // (BATCH, SIZE)
{
    const int tid = threadIdx.x;
    const int l   = tid & 63;
    const int w   = tid >> 6;            // wave 0..3
    const int q   = l & 31;
    const int bh  = l >> 5;              // 0/1
    const int jc  = blockIdx.x & 7;      // 8 j-chunks of JCH=16
    const int bc  = blockIdx.x >> 3;     // 128 b-chunks of BB=8
    const int b   = bc*BB + w*2 + bh;
    const int j0  = jc*JCH;
    const int i0  = q*4;                 // 4 consecutive i per thread (the diff)
    const float c6 = 0.16666667f;

    // ---- per-thread setup (once; amortized over JCH j's) ----
    // grid row from this thread's own first element (all rows identical by construction)
    const int   e00 = j0*IN_DIM + i0;
    const float g0  = grid[(size_t)e00*NG + 0];
    const float g5  = grid[(size_t)e00*NG + 5];
    const float h   = (g5 - g0) * 0.2f;
    const float t0  = g0 - 3.0f*h;
    const float ih  = 1.0f/h;

    const f4 xv = *(const f4*)(x + (size_t)b*IN_DIM + i0);
    float base[4], B8[4][8];
    #pragma unroll
    for (int c = 0; c < 4; ++c) {
        const float v = xv[c];
        base[c] = __fdividef(v, 1.0f + __expf(-v));     // silu (once, not per j)

        const float s  = (v - t0)*ih;
        const float okf = (s >= 0.0f && s < 11.0f) ? 1.0f : 0.0f;
        int m = (int)s;
        m = (m < 0) ? 0 : ((m > 10) ? 10 : m);
        const float u  = s - (float)m;
        const float u2 = u*u, u3 = u2*u, om = 1.0f - u;
        const float N0 = om*om*om*c6 * okf;
        const float N1 = fmaf(3.0f, u3, fmaf(-6.0f, u2, 4.0f))*c6 * okf;
        const float N2 = fmaf(-3.0f, u3, fmaf(3.0f, u2, fmaf(3.0f, u, 1.0f)))*c6 * okf;
        const float N3 = u3*c6 * okf;

        #pragma unroll
        for (int k = 0; k < 8; ++k) {
            const int d = k - m + 3;     // which basis fn covers coef k (0..3), else 0
            float bk = 0.0f;
            bk = (d == 0) ? N0 : bk;
            bk = (d == 1) ? N1 : bk;
            bk = (d == 2) ? N2 : bk;
            bk = (d == 3) ? N3 : bk;
            B8[c][k] = bk;
        }
    }

    // ---- j loop (same structure as baseline; unroll 1) ----
    #pragma unroll 1
    for (int jj = 0; jj < JCH; ++jj) {
        const int j = j0 + jj;
        const int e = j*IN_DIM + i0;
        const size_t off = (size_t)b*SIZE_ + (size_t)e;

        const f4* cfp = (const f4*)(coef + (size_t)e*NC);  // 4 rows x 32B contiguous
        const f4 sb4 = *(const f4*)(scale_base + e);
        const f4 ss4 = *(const f4*)(scale_sp   + e);
        const f4 mk4 = *(const f4*)(mask       + e);

        f4 sp4, y4;
        #pragma unroll
        for (int c = 0; c < 4; ++c) {
            const f4 ca = cfp[2*c], cb = cfp[2*c + 1];     // L1/L2-hot
            float s = B8[c][0]*ca[0];
            s = fmaf(B8[c][1], ca[1], s);
            s = fmaf(B8[c][2], ca[2], s);
            s = fmaf(B8[c][3], ca[3], s);
            s = fmaf(B8[c][4], cb[0], s);
            s = fmaf(B8[c][5], cb[1], s);
            s = fmaf(B8[c][6], cb[2], s);
            s = fmaf(B8[c][7], cb[3], s);
            sp4[c] = s;

            float y = sb4[c]*base[c];
            y = fmaf(ss4[c], s, y);
            y = mk4[c]*y;
            y4[c] = y;
        }

        *(f4*)(preacts    + off) = xv;
        *(f4*)(postspline + off) = sp4;
        *(f4*)(postacts   + off) = y4;

        float t = y4[0];                 // same sequential order as baseline
        t += y4[1]; t += y4[2]; t += y4[3];
        // 5-level butterfly; offsets <32 keep lanes within their 32-lane half
        #pragma unroll
        for (int o = 16; o > 0; o >>= 1) t += __shfl_xor(t, o, 64);
        if (q == 0) y_out[(size_t)b*OUT_DIM + j] = t;
    }
}

extern "C" void kernel_launch(void* const* d_in, const int* in_sizes, int n_in,
                              void* d_out, int out_size, void* d_ws, size_t ws_size,
                              hipStream_t stream) {
    const float* x    = (const float*)d_in[0];
    const float* grid = (const float*)d_in[1];
    const float* coef = (const float*)d_in[2];
    const float* sb   = (const float*)d_in[3];
    const float* ss   = (const float*)d_in[4];
    const float* mk   = (const float*)d_in[5];

    float* out        = (float*)d_out;
    float* y_out      = out;                          // 1024*128
    float* preacts    = y_out + BATCH*OUT_DIM;        // 1024*16384
    float* postacts   = preacts + (size_t)BATCH*SIZE_;
    float* postspline = postacts + (size_t)BATCH*SIZE_;

    // 8 j-chunks x 128 b-chunks = 1024 blocks = 4/CU (16 waves/CU), LDS-free
    kan_fused<<<1024, 256, 0, stream>>>(x, grid, coef, sb, ss, mk,
                                        y_out, preacts, postacts, postspline);
}